// Round 7
// baseline (123.538 us; speedup 1.0000x reference)
//
#include <hip/hip_runtime.h>

#define BB 64
#define NN 64
#define TT 100
#define TQ 4                  // consecutive t's per block
#define NTQ (TT / TQ)         // 25 t-chunks
#define CNT_OFF (NTQ * NN * BB)   // counters live after the 400 KB partials

// Broadcast lane `lane`'s value of v to all 64 lanes via v_readlane.
__device__ __forceinline__ float bcast(float v, int lane) {
    return __int_as_float(__builtin_amdgcn_readlane(__float_as_int(v), lane));
}

// Block = (n, t0..t0+3) tile, 256 threads / 4 waves. Phases 1-2 identical to R6
// (coalesced x stage + readlane argmin). Phase 3: block writes its partial row,
// takes a ticket on cnt[n]; the 25th arriver reduces all partials for n and
// writes out[:,n] — fuses the old reduce kernel into the slice kernel, removing
// the inter-kernel grid drain (R6 post-mortem: ~4-6 us of node gap + ramp).
__global__ __launch_bounds__(256) void social_fused_kernel(
    const float* __restrict__ x,          // (B, N, T, 6) f32
    const float* __restrict__ wfa,        // (B, 3, 3)    f32
    const int* __restrict__ rand_idx,     // (T*N, B)     i32 in [0, B-2]
    const int* __restrict__ drop_mask,    // (T*N, B)     bool stored as i32
    float* __restrict__ ws,               // (NTQ, NN, BB) partials
    unsigned* __restrict__ cnt,           // (NN) tickets, pre-zeroed
    float* __restrict__ out)              // (B, N)
{
    const int n  = blockIdx.x & 63;       // grid = NTQ*64 blocks
    const int tq = blockIdx.x >> 6;       // 0..24
    const int t0 = tq * TQ;

    __shared__ float2 S[TQ][BB + 1];
    __shared__ float  Rld[TQ][BB];
    __shared__ int    islast;

    // ---- phase 1: coalesced load + transform ----
    {
        const int lb = threadIdx.x >> 2;  // 0..63
        const int k  = threadIdx.x & 3;   // 0..3
        const float* wp = wfa + lb * 9;
        const float r00 = wp[0], r01 = wp[1], tx = wp[2];
        const float r10 = wp[3], r11 = wp[4], ty = wp[5];
        const size_t xoff = (((size_t)lb * NN + n) * (size_t)TT + (size_t)(t0 + k)) * 6;
        const float2 p = *(const float2*)(x + xoff);
        const float gx = r00 * p.x + r01 * p.y + tx;
        const float gy = r10 * p.x + r11 * p.y + ty;
        S[k][lb] = make_float2(gx, gy);
    }
    __syncthreads();

    // ---- phase 2: wave w handles slice t = t0 + w (bit-identical to R6) ----
    const int w = threadIdx.x >> 6;
    const int b = threadIdx.x & 63;
    const int t = t0 + w;
    const int s = t * NN + n;
    const size_t sb = (size_t)s * BB + b;
    const int r  = rand_idx[sb];
    const int dm = drop_mask[sb];

    const float2 g = S[w][b];
    const float gx = g.x, gy = g.y;
    const float sq = gx * gx + gy * gy;

    float bd0 = 3.4e38f, bd1 = 3.4e38f, bd2 = 3.4e38f, bd3 = 3.4e38f;
    int   bi0 = 0, bi1 = 16, bi2 = 32, bi3 = 48;
    #pragma unroll
    for (int i = 0; i < 16; ++i) {
        {
            const int c = i;
            const float qx = bcast(gx, c), qy = bcast(gy, c), qz = bcast(sq, c);
            float d2 = fmaf(-2.0f, fmaf(gx, qx, gy * qy), sq + qz);
            d2 = fmaxf(d2, 1e-12f);
            const bool take = (c != b) && (d2 < bd0);
            bd0 = take ? d2 : bd0;  bi0 = take ? c : bi0;
        }
        {
            const int c = 16 + i;
            const float qx = bcast(gx, c), qy = bcast(gy, c), qz = bcast(sq, c);
            float d2 = fmaf(-2.0f, fmaf(gx, qx, gy * qy), sq + qz);
            d2 = fmaxf(d2, 1e-12f);
            const bool take = (c != b) && (d2 < bd1);
            bd1 = take ? d2 : bd1;  bi1 = take ? c : bi1;
        }
        {
            const int c = 32 + i;
            const float qx = bcast(gx, c), qy = bcast(gy, c), qz = bcast(sq, c);
            float d2 = fmaf(-2.0f, fmaf(gx, qx, gy * qy), sq + qz);
            d2 = fmaxf(d2, 1e-12f);
            const bool take = (c != b) && (d2 < bd2);
            bd2 = take ? d2 : bd2;  bi2 = take ? c : bi2;
        }
        {
            const int c = 48 + i;
            const float qx = bcast(gx, c), qy = bcast(gy, c), qz = bcast(sq, c);
            float d2 = fmaf(-2.0f, fmaf(gx, qx, gy * qy), sq + qz);
            d2 = fmaxf(d2, 1e-12f);
            const bool take = (c != b) && (d2 < bd3);
            bd3 = take ? d2 : bd3;  bi3 = take ? c : bi3;
        }
    }
    float best = bd0; int besti = bi0;
    if (bd1 < best) { best = bd1; besti = bi1; }
    if (bd2 < best) { best = bd2; besti = bi2; }
    if (bd3 < best) { best = bd3; besti = bi3; }

    const int rnb = r + (r >= b ? 1 : 0);
    const int nb  = dm ? rnb : besti;

    const float qx = __shfl(gx, nb);
    const float qy = __shfl(gy, nb);
    const float qz = __shfl(sq, nb);
    const float dot = fmaf(gx, qx, gy * qy);
    const float d2m = fmaxf(fmaf(-2.0f, dot, sq + qz), 1e-12f);
    const float nd = sqrtf(d2m);
    const float diff = nd - 1.5f;
    Rld[w][b] = diff * diff;
    __syncthreads();

    // ---- phase 3: publish partial row + ticket ----
    if (w == 0) {
        const float sum4 = ((Rld[0][b] + Rld[1][b]) + Rld[2][b]) + Rld[3][b];
        __hip_atomic_store(&ws[((size_t)tq * NN + n) * BB + b], sum4,
                           __ATOMIC_RELAXED, __HIP_MEMORY_SCOPE_AGENT);
        __threadfence();                          // release: partials visible device-wide
        if (b == 0) {
            const unsigned old = __hip_atomic_fetch_add(
                &cnt[n], 1u, __ATOMIC_ACQ_REL, __HIP_MEMORY_SCOPE_AGENT);
            islast = (old == NTQ - 1) ? 1 : 0;
        }
    }
    __syncthreads();
    if (!islast) return;

    // ---- tail (exactly one block per n): reduce 25 partial rows ----
    __threadfence();                              // acquire: invalidate stale L1/L2
    float acc = 0.f;
    for (int tqq = w; tqq < NTQ; tqq += TQ)       // w=0:7 rows, w=1..3:6 rows
        acc += __hip_atomic_load(&ws[((size_t)tqq * NN + n) * BB + b],
                                 __ATOMIC_RELAXED, __HIP_MEMORY_SCOPE_AGENT);
    __syncthreads();                              // Rld reuse safe (all past barrier above)
    Rld[w][b] = acc;
    __syncthreads();
    if (w == 0)
        out[b * NN + n] = (((Rld[0][b] + Rld[1][b]) + Rld[2][b]) + Rld[3][b]) * (1.0f / TT);
}

extern "C" void kernel_launch(void* const* d_in, const int* in_sizes, int n_in,
                              void* d_out, int out_size, void* d_ws, size_t ws_size,
                              hipStream_t stream) {
    const float* x = (const float*)d_in[0];
    const float* wfa = (const float*)d_in[1];
    const int* rand_idx = (const int*)d_in[2];
    const int* drop_mask = (const int*)d_in[3];
    float* out = (float*)d_out;
    float* ws = (float*)d_ws;                     // 400 KB partials + 256 B tickets
    unsigned* cnt = (unsigned*)((char*)d_ws + CNT_OFF * sizeof(float));

    // tickets must start at 0 every launch (ws is poisoned 0xAA) — 256 B fill
    hipMemsetAsync(cnt, 0, NN * sizeof(unsigned), stream);

    social_fused_kernel<<<NTQ * NN, 256, 0, stream>>>(
        x, wfa, rand_idx, drop_mask, ws, cnt, out);
}

// Round 8
// 70.492 us; speedup vs baseline: 1.7525x; 1.7525x over previous
//
#include <hip/hip_runtime.h>

#define BB 64
#define NN 64
#define TT 100
#define TQ 4                  // consecutive t's per block
#define NTQ (TT / TQ)         // 25 t-chunks

// Kernel 1: block = (n, t0..t0+3) tile, 256 threads / 4 waves (R6 structure —
// R7's fused variant regressed 47 us: per-block device-scope __threadfence
// caused an L2 writeback/invalidate storm across 8 XCDs).
// Phase 2 inner loop: min-ONLY (the loss needs the min distance VALUE, not the
// argmin index — ties give equal values), difference-form d2 from a
// wave-uniform ds_read_b64 broadcast (no per-iter address math, no readlane
// SGPR pressure): ~7 VALU + 1 LDS per c vs R6's ~13 VALU.
__global__ __launch_bounds__(256) void social_slice_kernel(
    const float* __restrict__ x,          // (B, N, T, 6) f32
    const float* __restrict__ wfa,        // (B, 3, 3)    f32
    const int* __restrict__ rand_idx,     // (T*N, B)     i32 in [0, B-2]
    const int* __restrict__ drop_mask,    // (T*N, B)     bool stored as i32
    float* __restrict__ ws)               // (NTQ, NN, BB) 4-t partial sums
{
    const int n  = blockIdx.x & 63;       // grid = NTQ*64 blocks
    const int tq = blockIdx.x >> 6;       // 0..24
    const int t0 = tq * TQ;

    __shared__ float2 S[TQ][BB + 1];      // (gx,gy) per (t,b); +1 pad for writes
    __shared__ float  Rld[TQ][BB];

    // ---- phase 1: coalesced load + transform ----
    {
        const int lb = threadIdx.x >> 2;  // 0..63
        const int k  = threadIdx.x & 3;   // 0..3
        const float* wp = wfa + lb * 9;
        const float r00 = wp[0], r01 = wp[1], tx = wp[2];
        const float r10 = wp[3], r11 = wp[4], ty = wp[5];
        const size_t xoff = (((size_t)lb * NN + n) * (size_t)TT + (size_t)(t0 + k)) * 6;
        const float2 p = *(const float2*)(x + xoff);   // even offset -> 8B aligned
        const float gx = r00 * p.x + r01 * p.y + tx;
        const float gy = r10 * p.x + r11 * p.y + ty;
        S[k][lb] = make_float2(gx, gy);
    }
    __syncthreads();

    // ---- phase 2: wave w handles slice t = t0 + w ----
    const int w = threadIdx.x >> 6;
    const int b = threadIdx.x & 63;
    const int t = t0 + w;
    const int s = t * NN + n;
    const size_t sb = (size_t)s * BB + b;
    const int r  = rand_idx[sb];          // coalesced, issued early
    const int dm = drop_mask[sb];

    const float2 g = S[w][b];             // stride-8B: 2 lanes/bank, free
    const float gx = g.x, gy = g.y;

    const float INF = __int_as_float(0x7f800000);
    // min over c != b of (gx-qx)^2 + (gy-qy)^2 ; 4 independent chains for ILP,
    // self excluded by cndmask to +inf. Clamp applied once after selection
    // (fmax/sqrt monotone => same result as ref's per-entry clamp).
    float m0 = INF, m1 = INF, m2 = INF, m3 = INF;
    #pragma unroll
    for (int i = 0; i < 16; ++i) {
        {
            const int c = i;
            const float2 q = S[w][c];     // wave-uniform addr -> broadcast
            const float dx = gx - q.x, dy = gy - q.y;
            float d2 = fmaf(dx, dx, dy * dy);
            d2 = (c == b) ? INF : d2;
            m0 = fminf(m0, d2);
        }
        {
            const int c = 16 + i;
            const float2 q = S[w][c];
            const float dx = gx - q.x, dy = gy - q.y;
            float d2 = fmaf(dx, dx, dy * dy);
            d2 = (c == b) ? INF : d2;
            m1 = fminf(m1, d2);
        }
        {
            const int c = 32 + i;
            const float2 q = S[w][c];
            const float dx = gx - q.x, dy = gy - q.y;
            float d2 = fmaf(dx, dx, dy * dy);
            d2 = (c == b) ? INF : d2;
            m2 = fminf(m2, d2);
        }
        {
            const int c = 48 + i;
            const float2 q = S[w][c];
            const float dx = gx - q.x, dy = gy - q.y;
            float d2 = fmaf(dx, dx, dy * dy);
            d2 = (c == b) ? INF : d2;
            m3 = fminf(m3, d2);
        }
    }
    const float best = fminf(fminf(m0, m1), fminf(m2, m3));

    // drop-lane neighbor distance: reference sq-form via shfl (exact ref path)
    const int rnb = r + (r >= b ? 1 : 0); // skip-self remap, never == b
    const float sq  = fmaf(gx, gx, gy * gy);
    const float qx  = __shfl(gx, rnb);
    const float qy  = __shfl(gy, rnb);
    const float qsq = __shfl(sq, rnb);
    const float d2r = fmaf(-2.0f, fmaf(gx, qx, gy * qy), sq + qsq);

    const float d2sel = dm ? d2r : best;
    const float nd = sqrtf(fmaxf(d2sel, 1e-12f));
    const float diff = nd - 1.5f;
    Rld[w][b] = diff * diff;
    __syncthreads();

    // ---- phase 3: combine the block's 4 t's, one coalesced 256 B store ----
    if (w == 0) {
        const float sum4 = ((Rld[0][b] + Rld[1][b]) + Rld[2][b]) + Rld[3][b];
        ws[((size_t)tq * NN + n) * BB + b] = sum4;
    }
}

// Kernel 2: out[b,n] = (1/T) * sum_tq ws[tq][n][b].  16 blocks x 256; lane=b coalesced.
__global__ __launch_bounds__(256) void social_reduce_kernel(
    const float* __restrict__ ws,
    float* __restrict__ out)              // (B, N)
{
    const int b = threadIdx.x & 63;
    const int n = blockIdx.x * 4 + (threadIdx.x >> 6);

    float acc = 0.f;
    #pragma unroll
    for (int tq = 0; tq < NTQ; ++tq)
        acc += ws[((size_t)tq * NN + n) * BB + b];
    out[b * NN + n] = acc * (1.0f / TT);
}

extern "C" void kernel_launch(void* const* d_in, const int* in_sizes, int n_in,
                              void* d_out, int out_size, void* d_ws, size_t ws_size,
                              hipStream_t stream) {
    const float* x = (const float*)d_in[0];
    const float* wfa = (const float*)d_in[1];
    const int* rand_idx = (const int*)d_in[2];
    const int* drop_mask = (const int*)d_in[3];
    float* out = (float*)d_out;
    float* ws = (float*)d_ws;             // needs 25*64*64*4 = 400 KB

    social_slice_kernel<<<NTQ * NN, 256, 0, stream>>>(
        x, wfa, rand_idx, drop_mask, ws);
    social_reduce_kernel<<<NN / 4, 256, 0, stream>>>(ws, out);
}